// Round 9
// baseline (67.592 us; speedup 1.0000x reference)
//
#include <hip/hip_runtime.h>

#define N_LAYERS 512
#define DEL_Z (0.9f / 512.0f)

// Compile-time z-constants (double-evaluated, folded to f32 literals after
// full unroll). k(l) = 1/(1 - DEL_Z*l).
constexpr double DZD = 0.9 / 512.0;
__host__ __device__ constexpr float K1f(int l) {          // = -DEL_Z*k^2  ( = d1*PiT )
    double k = 1.0 / (1.0 - DZD * (double)l);
    return (float)(-DZD * k * k);
}
__host__ __device__ constexpr float K2f(int l) {          // = k(l+1)-k(l) ( = dl*PiT )
    double k  = 1.0 / (1.0 - DZD * (double)l);
    double kn = 1.0 / (1.0 - DZD * (double)(l + 1));
    return (float)(kn - k);
}
__host__ __device__ constexpr float K3f(int l) {          // = DEL_Z*z^2   ( c4p = K3*r1 )
    double z = DZD * (double)l;
    return (float)(DZD * z * z);
}

// Exact-algebra scan, carrying T = PiT*(Re + inv1(l))  (PiT factors out of all
// z-constants; identity inv2/PiT == inv1^2 collapses c3 to r1^2 = 1/b1^2):
//   e  = c0 + 2*DEL_Z*om*Im
//   U  = e*T + K1_l                      ( = PiT*(Rn + inv1(l)) )
//   u  = U/PiT
//   s  = Im^2 - u^2 + r1*(r1 + K3_l*phi),  phi = -1/(DEL_Z*om^2)
//   Im'= c0*Im + DEL_Z*om*s
//   T' = U + K2_l
// Broadcast constants per layer: just {c0, r1} = 8 B/lane (R1/R5/R8 were
// LDS-return-bus-bound at 20 B/lane/layer ~= 102 cy/layer/CU).
#define STEP(C0, R1, L)                                         \
    {                                                           \
        const float e  = fmaf(dz2om, Im, (C0));                 \
        const float U  = fmaf(e, T, K1f(L));                    \
        const float u  = U * ip;                                \
        const float pk = K3f(L) * phi;                          \
        const float w  = (R1) + pk;                             \
        const float cw = (R1) * w;                              \
        float s = fmaf(Im, Im, cw);                             \
        s = fmaf(-u, u, s);                                     \
        const float bm = (C0) * Im;                             \
        Im = fmaf(dzom, s, bm);                                 \
        T  = U + K2f(L);                                        \
    }

__global__ __launch_bounds__(256) void metric_scan_kernel(
    const float* __restrict__ Re_s, const float* __restrict__ Im_s,
    const float* __restrict__ omega, const float* __restrict__ PiT_p,
    const float* __restrict__ B, float* __restrict__ out, int n)
{
    __shared__ float2 cg[N_LAYERS];   // {c0, r1} per layer, 4 KB

    for (int l = threadIdx.x; l < N_LAYERS; l += 256) {
        const float b1 = B[l];
        const float b2 = B[l + 1];
        cg[l] = make_float2(2.0f - b2 / b1, 1.0f / b1);
    }
    __syncthreads();

    const int i = blockIdx.x * 256 + threadIdx.x;
    float Im = Im_s[i];
    const float om   = omega[i];
    const float PiT  = PiT_p[0];
    const float ip   = 1.0f / PiT;
    const float dzom = DEL_Z * om;
    const float dz2om = 2.0f * dzom;
    const float iom  = 1.0f / om;
    const float phi  = -(iom * iom) * (512.0f / 0.9f);   // -1/(DEL_Z*om^2)
    float T = fmaf(PiT, Re_s[i], 1.0f);                  // PiT*Re + k(0), k(0)=1

    // cf4[j] = {c0,r1} of layers 2j and 2j+1 -> one b128 per 2 layers,
    // dist-1 register double-buffer (R5's proven scheme).
    const float4* cf4 = (const float4*)cg;
    float4 bA = cf4[0];
    float4 bB = cf4[1];

    #pragma unroll
    for (int g = 0; g < N_LAYERS / 4; ++g) {
        const int j2 = (2 * g + 2 < N_LAYERS / 2) ? 2 * g + 2 : N_LAYERS / 2 - 1;
        const int j3 = (2 * g + 3 < N_LAYERS / 2) ? 2 * g + 3 : N_LAYERS / 2 - 1;
        const float4 nA = cf4[j2];      // prefetch next group (clamped, no OOB)
        const float4 nB = cf4[j3];
        STEP(bA.x, bA.y, 4 * g + 0)
        STEP(bA.z, bA.w, 4 * g + 1)
        STEP(bB.x, bB.y, 4 * g + 2)
        STEP(bB.z, bB.w, 4 * g + 3)
        bA = nA; bB = nB;
    }

    // Re_f = (T - k(512))/PiT, k(512) = 1/(1-0.9) = 10
    out[i]     = (T - 10.0f) * ip;
    out[n + i] = Im;
}

extern "C" void kernel_launch(void* const* d_in, const int* in_sizes, int n_in,
                              void* d_out, int out_size, void* d_ws, size_t ws_size,
                              hipStream_t stream)
{
    const float* Re_s  = (const float*)d_in[0];
    const float* Im_s  = (const float*)d_in[1];
    const float* omega = (const float*)d_in[2];
    const float* PiT   = (const float*)d_in[3];
    const float* B     = (const float*)d_in[4];
    float* out = (float*)d_out;
    const int n = in_sizes[0];                  // 131072
    metric_scan_kernel<<<n / 256, 256, 0, stream>>>(Re_s, Im_s, omega, PiT, B, out, n);
}